// Round 5
// baseline (188.066 us; speedup 1.0000x reference)
//
#include <hip/hip_runtime.h>
#include <stdint.h>

// ---------------------------------------------------------------------------
// Fused causal self-attention block: qkv = x@Wqkv, RoPE(q,k), SDPA, out@Wout
// B=2 T=2048 C=1024 H=16 Dh=64.  bf16 MFMA compute, fp32 accum/softmax.
// ---------------------------------------------------------------------------

typedef __attribute__((ext_vector_type(8))) __bf16 bf16x8;
typedef __attribute__((ext_vector_type(4))) __bf16 bf16x4;
typedef __attribute__((ext_vector_type(4))) float f32x4;

#define MFMA16(a, b, c) __builtin_amdgcn_mfma_f32_16x16x32_bf16((a), (b), (c), 0, 0, 0)

#define SWAIT_VM8()                                     \
    do {                                                \
        asm volatile("s_waitcnt vmcnt(8)" ::: "memory");\
        __builtin_amdgcn_sched_barrier(0);              \
    } while (0)
#define SWAIT_LGKM0()                                     \
    do {                                                  \
        asm volatile("s_waitcnt lgkmcnt(0)" ::: "memory");\
        __builtin_amdgcn_sched_barrier(0);                \
    } while (0)

__device__ __forceinline__ void gl_lds16(const void* g, void* l) {
    __builtin_amdgcn_global_load_lds(
        (const __attribute__((address_space(1))) void*)g,
        (__attribute__((address_space(3))) void*)l, 16, 0, 0);
}

__device__ __forceinline__ unsigned short f2bf(float f) {
    union { float f; unsigned u; } x; x.f = f;
    unsigned r = x.u + 0x7FFFu + ((x.u >> 16) & 1u);   // RNE
    return (unsigned short)(r >> 16);
}
__device__ __forceinline__ float bf2f(unsigned short h) {
    union { unsigned u; float f; } x; x.u = ((unsigned)h) << 16;
    return x.f;
}
__device__ __forceinline__ f32x4 fmax4(f32x4 a, f32x4 b) {
    f32x4 r;
#pragma unroll
    for (int i = 0; i < 4; i++) r[i] = fmaxf(a[i], b[i]);
    return r;
}

// ------------------------------- cast x -> bf16 ----------------------------
__global__ void cast_f32_bf16(const float* __restrict__ src,
                              unsigned short* __restrict__ dst, int n4) {
    int i = blockIdx.x * 256 + threadIdx.x;
    if (i >= n4) return;
    float4 v = ((const float4*)src)[i];
    ushort4 o;
    o.x = f2bf(v.x); o.y = f2bf(v.y); o.z = f2bf(v.z); o.w = f2bf(v.w);
    ((ushort4*)dst)[i] = o;
}

// ---------------------- transpose+cast weight: [K][N] -> [N][K] bf16 -------
__global__ void transpose_cast(const float* __restrict__ src,
                               unsigned short* __restrict__ dst, int K, int N) {
    __shared__ float tile[32][33];
    int n0 = blockIdx.x * 32, k0 = blockIdx.y * 32;
    int r = threadIdx.x >> 5, c = threadIdx.x & 31;   // 8 rows x 32 cols
#pragma unroll
    for (int i = 0; i < 4; i++) {
        int kk = r + i * 8;
        tile[kk][c] = src[(size_t)(k0 + kk) * N + n0 + c];
    }
    __syncthreads();
#pragma unroll
    for (int i = 0; i < 4; i++) {
        int nn = r + i * 8;
        dst[(size_t)(n0 + nn) * K + k0 + c] = f2bf(tile[c][nn]);
    }
}

// ---------------- RoPE tables, interleaved (cos,sin) per (t,d) -------------
__global__ void rope_tables(float2* __restrict__ cst) {
    int idx = blockIdx.x * 256 + threadIdx.x;   // 2048*32 entries
    int t = idx >> 5, d = idx & 31;
    float inv = powf(10000.0f, -(float)(2 * d) / 64.0f);
    float a = (float)t * inv;
    cst[idx] = make_float2(cosf(a), sinf(a));
}

// ------------------------------ GEMM: C = A @ Bt^T --------------------------
// A [M][K] bf16 row-major, Bt [N][K] bf16.  128x128 tile, BK=64, 4 waves.
// global_load_lds staging (16B) with pre-swizzled source; swizzled ds_read.
// MODE 0: epilogue applies RoPE(+softmax scale on q) and scatters
//         q [B,H,T,Dh], k [B,H,T,Dh], v^T [B,H,Dh,T]  (bf16)
// MODE 1: plain fp32 store [M][N]
template <int MODE>
__global__ __launch_bounds__(256) void gemm_bt(
    const unsigned short* __restrict__ A,
    const unsigned short* __restrict__ Bt,
    unsigned short* __restrict__ oq,
    unsigned short* __restrict__ ok,
    unsigned short* __restrict__ ovt,
    float* __restrict__ of,
    const float2* __restrict__ cst,
    int M_, int N_, int K_) {
    __shared__ __attribute__((aligned(16))) unsigned short ldsA[128 * 64];
    __shared__ __attribute__((aligned(16))) unsigned short ldsB[128 * 64];
    const int tid = threadIdx.x;
    const int lane = tid & 63, wv = tid >> 6;
    const int wr = wv >> 1, wc = wv & 1;
    const int l15 = lane & 15, lg = lane >> 4;
    const int lrow = lane >> 3, lch = lane & 7;
    const int swz = (lch * 16) ^ (lrow << 4);
    const int m0 = blockIdx.x * 128, n0 = blockIdx.y * 128;
    const char* Ab = (const char*)A;
    const char* Bb = (const char*)Bt;
    const size_t rstride = (size_t)K_ * 2;

    f32x4 acc[4][4] = {};

    const int nkt = K_ >> 6;
    for (int kt = 0; kt < nkt; kt++) {
        if (kt) __syncthreads();
#pragma unroll
        for (int ii = 0; ii < 4; ii++) {
            int r0 = wv * 32 + ii * 8;
            gl_lds16(Ab + (size_t)(m0 + r0 + lrow) * rstride + kt * 128 + swz,
                     (char*)ldsA + r0 * 128);
            gl_lds16(Bb + (size_t)(n0 + r0 + lrow) * rstride + kt * 128 + swz,
                     (char*)ldsB + r0 * 128);
        }
        __syncthreads();   // compiler drains vmcnt(0) before s_barrier
#pragma unroll
        for (int ks = 0; ks < 2; ks++) {
            const int kb = ks * 64 + lg * 16;
            bf16x8 af[4], bfr[4];
#pragma unroll
            for (int mf = 0; mf < 4; mf++) {
                int row = wr * 64 + mf * 16 + l15;
                af[mf] = *(const bf16x8*)((const char*)ldsA + row * 128 +
                                          (kb ^ ((row & 7) << 4)));
            }
#pragma unroll
            for (int nf = 0; nf < 4; nf++) {
                int row = wc * 64 + nf * 16 + l15;
                bfr[nf] = *(const bf16x8*)((const char*)ldsB + row * 128 +
                                           (kb ^ ((row & 7) << 4)));
            }
#pragma unroll
            for (int mf = 0; mf < 4; mf++)
#pragma unroll
                for (int nf = 0; nf < 4; nf++)
                    acc[mf][nf] = MFMA16(af[mf], bfr[nf], acc[mf][nf]);
        }
    }

    // epilogue.  C/D layout: col = lane&15, row = (lane>>4)*4 + reg  [m89/m91]
    if (MODE == 0) {
        const int sblk = n0 >> 10;                 // 0=q 1=k 2=v, block-uniform
        if (sblk == 2) {
#pragma unroll
            for (int mf = 0; mf < 4; mf++)
#pragma unroll
                for (int nf = 0; nf < 4; nf++)
#pragma unroll
                    for (int j = 0; j < 4; j++) {
                        int grow = m0 + wr * 64 + mf * 16 + lg * 4 + j;
                        int gcol = n0 + wc * 64 + nf * 16 + l15;
                        int b = grow >> 11, t = grow & 2047;
                        int c = gcol & 1023;
                        int h = c >> 6, d = c & 63;
                        int hb = b * 16 + h;
                        ovt[((size_t)hb * 64 + d) * 2048 + t] =
                            f2bf(acc[mf][nf][j]);
                    }
        } else {
            const float QSC = 0.125f * 1.44269504f;  // scale * log2(e)
            unsigned short* dst = (sblk == 0) ? oq : ok;
#pragma unroll
            for (int mf = 0; mf < 4; mf++)
#pragma unroll
                for (int j = 0; j < 4; j++) {
                    int grow = m0 + wr * 64 + mf * 16 + lg * 4 + j;
                    int b = grow >> 11, t = grow & 2047;
#pragma unroll
                    for (int nf = 0; nf < 2; nf++) {
                        int gcol = n0 + wc * 64 + nf * 16 + l15;
                        int c = gcol & 1023;
                        int h = c >> 6;
                        int d = nf * 16 + l15;           // < 32
                        int hb = b * 16 + h;
                        float2 csv = cst[t * 32 + d];
                        float x1 = acc[mf][nf][j];       // dim d
                        float x2 = acc[mf][nf + 2][j];   // dim d+32
                        float r1 = x1 * csv.x - x2 * csv.y;
                        float r2 = x2 * csv.x + x1 * csv.y;
                        if (sblk == 0) { r1 *= QSC; r2 *= QSC; }
                        size_t base = ((size_t)hb * 2048 + t) * 64;
                        dst[base + d] = f2bf(r1);
                        dst[base + d + 32] = f2bf(r2);
                    }
                }
        }
    } else {
#pragma unroll
        for (int mf = 0; mf < 4; mf++)
#pragma unroll
            for (int nf = 0; nf < 4; nf++)
#pragma unroll
                for (int j = 0; j < 4; j++) {
                    int grow = m0 + wr * 64 + mf * 16 + lg * 4 + j;
                    int gcol = n0 + wc * 64 + nf * 16 + l15;
                    of[(size_t)grow * N_ + gcol] = acc[mf][nf][j];
                }
    }
}

// ------------------------------ flash attention ----------------------------
// 2048 blocks x 64 thr (1 wave).  Each wave owns one 32-row q-tile and its
// FULL key range (no split-k).  K tiles staged via global_load_lds into an
// 8KB LDS buffer one tile ahead (counted vmcnt(8) keeps V loads in flight);
// V fragments load straight global->VGPR one tile ahead (consumed at tile
// end -> latency hidden).  Swapped QK^T, P round-trip via 4KB LDS,
// defer-max (T13), setprio on MFMA.  12KB LDS + ~150 VGPR -> 3 waves/SIMD.
__global__ __launch_bounds__(64, 3) void attn_fwd(
    const unsigned short* __restrict__ Q,
    const unsigned short* __restrict__ K,
    const unsigned short* __restrict__ Vt,
    unsigned short* __restrict__ O) {
    __shared__ __attribute__((aligned(16))) char KbL[8192];
    __shared__ __attribute__((aligned(16))) char Pb[4096];
    const int lane = threadIdx.x & 63;
    const int l15 = lane & 15, lg = lane >> 4;
    const int lrow = lane >> 3, lch = lane & 7;
    const int swz = (lch * 16) ^ (lrow << 4);

    // mapping: 4 bh per XCD (2MB K+V working set per L2); jt paired {j,63-j}
    // so any contiguous run of blocks is load-balanced.
    const int wg = blockIdx.x;            // 0..2047
    const int xcd = wg & 7, r = wg >> 3;  // r 0..255
    const int bh = xcd * 4 + (r & 3);
    const int p = r >> 2;                 // 0..63
    const int jt = (p & 1) ? (63 - (p >> 1)) : (p >> 1);
    const int q0 = jt * 32;
    const int nkt = (jt >> 1) + 1;
    const int b = bh >> 4, h = bh & 15;

    const unsigned short* Qh = Q + (size_t)bh * 2048 * 64;
    const char* Kg = (const char*)(K + (size_t)bh * 2048 * 64);
    const unsigned short* Vh = Vt + (size_t)bh * 64 * 2048;

    bf16x8 qa[2][2];
#pragma unroll
    for (int mf = 0; mf < 2; mf++)
#pragma unroll
        for (int ks = 0; ks < 2; ks++)
            qa[mf][ks] = *(const bf16x8*)(Qh + (size_t)(q0 + mf * 16 + l15) * 64 +
                                          ks * 32 + lg * 8);

    auto stageK = [&](int k0) {
        const char* kg = Kg + (size_t)k0 * 128;   // K rows contiguous (128B)
#pragma unroll
        for (int ii = 0; ii < 8; ii++)
            gl_lds16(kg + (ii * 8 + lrow) * 128 + swz, KbL + ii * 1024);
    };

    f32x4 oacc[2][4] = {};
    float mi[2] = {-1e30f, -1e30f}, li[2] = {0.f, 0.f};
    bf16x8 vb[2][4];

#define LOADV(K0)                                                             \
    do {                                                                      \
        _Pragma("unroll") for (int ks = 0; ks < 2; ks++)                      \
            _Pragma("unroll") for (int df = 0; df < 4; df++)                  \
                vb[ks][df] = *(const bf16x8*)(                                \
                    Vh + (size_t)(df * 16 + l15) * 2048 + (K0) + ks * 32 +    \
                    lg * 8);                                                  \
    } while (0)

    stageK(0);      // 8 gl_lds (K DMA)
    LOADV(0);       // 8 global_load (V regs) -- issued after K: vmcnt order
    for (int kt = 0; kt < nkt; ++kt) {
        const int k0 = kt * 64;
        SWAIT_VM8();   // K(kt) DMA landed; V loads may remain in flight
        bf16x8 kb[2][4];
#pragma unroll
        for (int ks = 0; ks < 2; ks++)
#pragma unroll
            for (int nf = 0; nf < 4; nf++) {
                int row = nf * 16 + l15;
                kb[ks][nf] = *(const bf16x8*)(
                    KbL + row * 128 + ((ks * 64 + lg * 16) ^ ((row & 7) << 4)));
            }
        // ---- S^T = K Q^T : col(l15)=q-row, row(lg*4+j)=key ----
        f32x4 s[2][4] = {};
        __builtin_amdgcn_s_setprio(1);
#pragma unroll
        for (int ks = 0; ks < 2; ks++)
#pragma unroll
            for (int mf = 0; mf < 2; mf++)
#pragma unroll
                for (int nf = 0; nf < 4; nf++)
                    s[mf][nf] = MFMA16(kb[ks][nf], qa[mf][ks], s[mf][nf]);
        __builtin_amdgcn_s_setprio(0);
        SWAIT_LGKM0();                       // kb drained -> LDS reusable
        const bool last = (kt == nkt - 1);
        if (!last) stageK(k0 + 64);          // K DMA prefetch (hides under
                                             // softmax+PV of this tile)
        // ---- online softmax (log2 domain; Q pre-scaled by QSC) ----
#pragma unroll
        for (int mf = 0; mf < 2; mf++) {
            if (last) {
                int qrow = q0 + mf * 16 + l15;
#pragma unroll
                for (int nf = 0; nf < 4; nf++)
#pragma unroll
                    for (int j = 0; j < 4; j++)
                        if (k0 + nf * 16 + lg * 4 + j > qrow)
                            s[mf][nf][j] = -1e30f;
            }
            f32x4 t01 = fmax4(s[mf][0], s[mf][1]);
            f32x4 t23 = fmax4(s[mf][2], s[mf][3]);
            f32x4 tm = fmax4(t01, t23);
            float rmax = fmaxf(fmaxf(tm[0], tm[1]), fmaxf(tm[2], tm[3]));
            if (__any(rmax > mi[mf] + 10.0f)) {   // defer-max (T13)
                rmax = fmaxf(rmax, __shfl_xor(rmax, 16));
                rmax = fmaxf(rmax, __shfl_xor(rmax, 32));
                float mnew = fmaxf(mi[mf], rmax);
                float alpha = exp2f(mi[mf] - mnew);
                mi[mf] = mnew;
                li[mf] *= alpha;
#pragma unroll
                for (int j = 0; j < 4; j++) {
                    float aj = __shfl(alpha, lg * 4 + j);
#pragma unroll
                    for (int df = 0; df < 4; df++) oacc[mf][df][j] *= aj;
                }
            }
#pragma unroll
            for (int nf = 0; nf < 4; nf++)
#pragma unroll
                for (int j = 0; j < 4; j++)
                    s[mf][nf][j] = exp2f(s[mf][nf][j] - mi[mf]);
            f32x4 s01 = s[mf][0] + s[mf][1];
            f32x4 s23 = s[mf][2] + s[mf][3];
            f32x4 ss = s01 + s23;
            float rsum = (ss[0] + ss[1]) + (ss[2] + ss[3]);
            rsum += __shfl_xor(rsum, 16);
            rsum += __shfl_xor(rsum, 32);
            li[mf] += rsum;
            // P pack -> LDS (row mf*16+l15, swizzled)
#pragma unroll
            for (int nf = 0; nf < 4; nf++) {
                bf16x4 pk;
#pragma unroll
                for (int j = 0; j < 4; j++) pk[j] = (__bf16)s[mf][nf][j];
                int row = mf * 16 + l15;
                *(bf16x4*)(Pb + row * 128 +
                           ((nf * 32 + lg * 8) ^ ((row & 7) << 4))) = pk;
            }
        }
        // ---- O += P @ V (same-wave DS in order; vb waited by compiler) ----
#pragma unroll
        for (int ks = 0; ks < 2; ks++) {
            bf16x8 pa[2];
#pragma unroll
            for (int mf = 0; mf < 2; mf++) {
                int row = mf * 16 + l15;
                pa[mf] = *(const bf16x8*)(
                    Pb + row * 128 + ((ks * 64 + lg * 16) ^ ((row & 7) << 4)));
            }
            __builtin_amdgcn_s_setprio(1);
#pragma unroll
            for (int mf = 0; mf < 2; mf++)
#pragma unroll
                for (int df = 0; df < 4; df++)
                    oacc[mf][df] = MFMA16(pa[mf], vb[ks][df], oacc[mf][df]);
            __builtin_amdgcn_s_setprio(0);
        }
        if (!last) LOADV(k0 + 64);   // V regs prefetch (consumed next PV)
    }
#undef LOADV

    // epilogue: O[b,t,h*64+d];  li lives at lane l15=row -> gather
#pragma unroll
    for (int mf = 0; mf < 2; mf++)
#pragma unroll
        for (int j = 0; j < 4; j++) {
            float lj = __shfl(li[mf], lg * 4 + j);
            float rl = 1.0f / lj;
            int t = q0 + mf * 16 + lg * 4 + j;
#pragma unroll
            for (int df = 0; df < 4; df++) {
                int d = df * 16 + l15;
                O[((size_t)(b * 2048 + t)) * 1024 + h * 64 + d] =
                    f2bf(oacc[mf][df][j] * rl);
            }
        }
}

// ---------------------------------------------------------------------------
extern "C" void kernel_launch(void* const* d_in, const int* in_sizes, int n_in,
                              void* d_out, int out_size, void* d_ws, size_t ws_size,
                              hipStream_t stream) {
    const float* x     = (const float*)d_in[0];
    const float* w_qkv = (const float*)d_in[1];
    const float* w_out = (const float*)d_in[2];
    float* out = (float*)d_out;
    char* ws = (char*)d_ws;
    const size_t MB = 1024 * 1024;

    unsigned short* xb    = (unsigned short*)(ws);             //  8 MB [4096][1024]
    unsigned short* wqkvt = (unsigned short*)(ws + 8 * MB);    //  6 MB [3072][1024]
    unsigned short* woutt = (unsigned short*)(ws + 14 * MB);   //  2 MB [1024][1024]
    unsigned short* qh    = (unsigned short*)(ws + 16 * MB);   //  8 MB [B,H,T,Dh]
    unsigned short* kh    = (unsigned short*)(ws + 24 * MB);   //  8 MB [B,H,T,Dh]
    unsigned short* vt    = (unsigned short*)(ws + 32 * MB);   //  8 MB [B,H,Dh,T]
    unsigned short* ao    = (unsigned short*)(ws + 40 * MB);   //  8 MB [4096][1024]
    float2* cst = (float2*)(ws + 48 * MB);                     // 512 KB

    cast_f32_bf16<<<4096, 256, 0, stream>>>(x, xb, (4096 * 1024) / 4);
    transpose_cast<<<dim3(96, 32), 256, 0, stream>>>(w_qkv, wqkvt, 1024, 3072);
    transpose_cast<<<dim3(32, 32), 256, 0, stream>>>(w_out, woutt, 1024, 1024);
    rope_tables<<<256, 256, 0, stream>>>(cst);

    gemm_bt<0><<<dim3(32, 24), 256, 0, stream>>>(xb, wqkvt, qh, kh, vt, nullptr,
                                                 cst, 4096, 3072, 1024);
    attn_fwd<<<2048, 64, 0, stream>>>(qh, kh, vt, ao);
    gemm_bt<1><<<dim3(32, 8), 256, 0, stream>>>(ao, woutt, nullptr, nullptr,
                                                nullptr, out, nullptr,
                                                4096, 1024, 1024);
}

// Round 6
// 137.798 us; speedup vs baseline: 1.3648x; 1.3648x over previous
//
#include <hip/hip_runtime.h>
#include <stdint.h>

// ---------------------------------------------------------------------------
// Fused causal self-attention block: qkv = x@Wqkv, RoPE(q,k), SDPA, out@Wout
// B=2 T=2048 C=1024 H=16 Dh=64.  bf16 MFMA compute, fp32 accum/softmax.
// ---------------------------------------------------------------------------

typedef __attribute__((ext_vector_type(8))) __bf16 bf16x8;
typedef __attribute__((ext_vector_type(4))) __bf16 bf16x4;
typedef __attribute__((ext_vector_type(4))) float f32x4;

#define MFMA16(a, b, c) __builtin_amdgcn_mfma_f32_16x16x32_bf16((a), (b), (c), 0, 0, 0)

#define SWAIT_VM0()                                     \
    do {                                                \
        asm volatile("s_waitcnt vmcnt(0)" ::: "memory");\
        __builtin_amdgcn_sched_barrier(0);              \
    } while (0)
#define SWAIT_LGKM0()                                     \
    do {                                                  \
        asm volatile("s_waitcnt lgkmcnt(0)" ::: "memory");\
        __builtin_amdgcn_sched_barrier(0);                \
    } while (0)

__device__ __forceinline__ void gl_lds16(const void* g, void* l) {
    __builtin_amdgcn_global_load_lds(
        (const __attribute__((address_space(1))) void*)g,
        (__attribute__((address_space(3))) void*)l, 16, 0, 0);
}

__device__ __forceinline__ unsigned short f2bf(float f) {
    union { float f; unsigned u; } x; x.f = f;
    unsigned r = x.u + 0x7FFFu + ((x.u >> 16) & 1u);   // RNE
    return (unsigned short)(r >> 16);
}
__device__ __forceinline__ float bf2f(unsigned short h) {
    union { unsigned u; float f; } x; x.u = ((unsigned)h) << 16;
    return x.f;
}
__device__ __forceinline__ f32x4 fmax4(f32x4 a, f32x4 b) {
    f32x4 r;
#pragma unroll
    for (int i = 0; i < 4; i++) r[i] = fmaxf(a[i], b[i]);
    return r;
}

// ------------------------------- cast x -> bf16 ----------------------------
__global__ void cast_f32_bf16(const float* __restrict__ src,
                              unsigned short* __restrict__ dst, int n4) {
    int i = blockIdx.x * 256 + threadIdx.x;
    if (i >= n4) return;
    float4 v = ((const float4*)src)[i];
    ushort4 o;
    o.x = f2bf(v.x); o.y = f2bf(v.y); o.z = f2bf(v.z); o.w = f2bf(v.w);
    ((ushort4*)dst)[i] = o;
}

// ---------------------- transpose+cast weight: [K][N] -> [N][K] bf16 -------
__global__ void transpose_cast(const float* __restrict__ src,
                               unsigned short* __restrict__ dst, int K, int N) {
    __shared__ float tile[32][33];
    int n0 = blockIdx.x * 32, k0 = blockIdx.y * 32;
    int r = threadIdx.x >> 5, c = threadIdx.x & 31;   // 8 rows x 32 cols
#pragma unroll
    for (int i = 0; i < 4; i++) {
        int kk = r + i * 8;
        tile[kk][c] = src[(size_t)(k0 + kk) * N + n0 + c];
    }
    __syncthreads();
#pragma unroll
    for (int i = 0; i < 4; i++) {
        int nn = r + i * 8;
        dst[(size_t)(n0 + nn) * K + k0 + c] = f2bf(tile[c][nn]);
    }
}

// ---------------- RoPE tables, interleaved (cos,sin) per (t,d) -------------
__global__ void rope_tables(float2* __restrict__ cst) {
    int idx = blockIdx.x * 256 + threadIdx.x;   // 2048*32 entries
    int t = idx >> 5, d = idx & 31;
    float inv = powf(10000.0f, -(float)(2 * d) / 64.0f);
    float a = (float)t * inv;
    cst[idx] = make_float2(cosf(a), sinf(a));
}

// ------------------------------ GEMM: C = A @ Bt^T --------------------------
// A [M][K] bf16 row-major, Bt [N][K] bf16.  128x128 tile, BK=64, 4 waves.
// global_load_lds staging (16B) with pre-swizzled source; swizzled ds_read.
// MODE 0: epilogue applies RoPE(+softmax scale on q) and scatters
//         q [B,H,T,Dh], k [B,H,T,Dh], v^T [B,H,Dh,T]  (bf16)
// MODE 1: plain fp32 store [M][N]
template <int MODE>
__global__ __launch_bounds__(256) void gemm_bt(
    const unsigned short* __restrict__ A,
    const unsigned short* __restrict__ Bt,
    unsigned short* __restrict__ oq,
    unsigned short* __restrict__ ok,
    unsigned short* __restrict__ ovt,
    float* __restrict__ of,
    const float2* __restrict__ cst,
    int M_, int N_, int K_) {
    __shared__ __attribute__((aligned(16))) unsigned short ldsA[128 * 64];
    __shared__ __attribute__((aligned(16))) unsigned short ldsB[128 * 64];
    const int tid = threadIdx.x;
    const int lane = tid & 63, wv = tid >> 6;
    const int wr = wv >> 1, wc = wv & 1;
    const int l15 = lane & 15, lg = lane >> 4;
    const int lrow = lane >> 3, lch = lane & 7;
    const int swz = (lch * 16) ^ (lrow << 4);
    const int m0 = blockIdx.x * 128, n0 = blockIdx.y * 128;
    const char* Ab = (const char*)A;
    const char* Bb = (const char*)Bt;
    const size_t rstride = (size_t)K_ * 2;

    f32x4 acc[4][4] = {};

    const int nkt = K_ >> 6;
    for (int kt = 0; kt < nkt; kt++) {
        if (kt) __syncthreads();
#pragma unroll
        for (int ii = 0; ii < 4; ii++) {
            int r0 = wv * 32 + ii * 8;
            gl_lds16(Ab + (size_t)(m0 + r0 + lrow) * rstride + kt * 128 + swz,
                     (char*)ldsA + r0 * 128);
            gl_lds16(Bb + (size_t)(n0 + r0 + lrow) * rstride + kt * 128 + swz,
                     (char*)ldsB + r0 * 128);
        }
        __syncthreads();   // compiler drains vmcnt(0) before s_barrier
#pragma unroll
        for (int ks = 0; ks < 2; ks++) {
            const int kb = ks * 64 + lg * 16;
            bf16x8 af[4], bfr[4];
#pragma unroll
            for (int mf = 0; mf < 4; mf++) {
                int row = wr * 64 + mf * 16 + l15;
                af[mf] = *(const bf16x8*)((const char*)ldsA + row * 128 +
                                          (kb ^ ((row & 7) << 4)));
            }
#pragma unroll
            for (int nf = 0; nf < 4; nf++) {
                int row = wc * 64 + nf * 16 + l15;
                bfr[nf] = *(const bf16x8*)((const char*)ldsB + row * 128 +
                                           (kb ^ ((row & 7) << 4)));
            }
#pragma unroll
            for (int mf = 0; mf < 4; mf++)
#pragma unroll
                for (int nf = 0; nf < 4; nf++)
                    acc[mf][nf] = MFMA16(af[mf], bfr[nf], acc[mf][nf]);
        }
    }

    // epilogue.  C/D layout: col = lane&15, row = (lane>>4)*4 + reg  [m89/m91]
    if (MODE == 0) {
        const int sblk = n0 >> 10;                 // 0=q 1=k 2=v, block-uniform
        if (sblk == 2) {
#pragma unroll
            for (int mf = 0; mf < 4; mf++)
#pragma unroll
                for (int nf = 0; nf < 4; nf++)
#pragma unroll
                    for (int j = 0; j < 4; j++) {
                        int grow = m0 + wr * 64 + mf * 16 + lg * 4 + j;
                        int gcol = n0 + wc * 64 + nf * 16 + l15;
                        int b = grow >> 11, t = grow & 2047;
                        int c = gcol & 1023;
                        int h = c >> 6, d = c & 63;
                        int hb = b * 16 + h;
                        ovt[((size_t)hb * 64 + d) * 2048 + t] =
                            f2bf(acc[mf][nf][j]);
                    }
        } else {
            const float QSC = 0.125f * 1.44269504f;  // scale * log2(e)
            unsigned short* dst = (sblk == 0) ? oq : ok;
#pragma unroll
            for (int mf = 0; mf < 4; mf++)
#pragma unroll
                for (int j = 0; j < 4; j++) {
                    int grow = m0 + wr * 64 + mf * 16 + lg * 4 + j;
                    int b = grow >> 11, t = grow & 2047;
#pragma unroll
                    for (int nf = 0; nf < 2; nf++) {
                        int gcol = n0 + wc * 64 + nf * 16 + l15;
                        int c = gcol & 1023;
                        int h = c >> 6;
                        int d = nf * 16 + l15;           // < 32
                        int hb = b * 16 + h;
                        float2 csv = cst[t * 32 + d];
                        float x1 = acc[mf][nf][j];       // dim d
                        float x2 = acc[mf][nf + 2][j];   // dim d+32
                        float r1 = x1 * csv.x - x2 * csv.y;
                        float r2 = x2 * csv.x + x1 * csv.y;
                        if (sblk == 0) { r1 *= QSC; r2 *= QSC; }
                        size_t base = ((size_t)hb * 2048 + t) * 64;
                        dst[base + d] = f2bf(r1);
                        dst[base + d + 32] = f2bf(r2);
                    }
                }
        }
    } else {
#pragma unroll
        for (int mf = 0; mf < 4; mf++)
#pragma unroll
            for (int nf = 0; nf < 4; nf++)
#pragma unroll
                for (int j = 0; j < 4; j++) {
                    int grow = m0 + wr * 64 + mf * 16 + lg * 4 + j;
                    int gcol = n0 + wc * 64 + nf * 16 + l15;
                    of[(size_t)grow * N_ + gcol] = acc[mf][nf][j];
                }
    }
}

// ------------------------------ flash attention ----------------------------
// 2048 blocks x 256 thr.  Block = ONE 32-row q-tile; its 4 waves split the
// key range 4-ways (flash-decoding within block) and merge via LDS at the
// end.  Inner loop is the round-2 proven structure verbatim: K and V tiles
// staged via global_load_lds into per-wave 16KB LDS slices one tile ahead
// (vmcnt(0) at tile top), swapped QK^T, P round-trip through a 2KB per-wave
// half-buffer (PV double-pumped ks=0,1).  launch_bounds(256,2) keeps VGPR
// budget at 128 so the prefetch stays in registers (the r3-r5 regression was
// launch_bounds(...,3) squeezing VGPR to 84 and sinking the prefetch).
// Dispatch: long q-tiles first, bh pinned per XCD.
__global__ __launch_bounds__(256, 2) void attn_fwd(
    const unsigned short* __restrict__ Q,
    const unsigned short* __restrict__ K,
    const unsigned short* __restrict__ Vt,
    unsigned short* __restrict__ O) {
    __shared__ __attribute__((aligned(16))) char ldsKV[4][16384];
    __shared__ __attribute__((aligned(16))) char ldsP[4][2048];
    __shared__ float ml[4][32][2];
    const int tid = threadIdx.x, lane = tid & 63, wv = tid >> 6;
    const int l15 = lane & 15, lg = lane >> 4;
    const int lrow = lane >> 3, lch = lane & 7;
    const int swz = (lch * 16) ^ (lrow << 4);

    const int wg = blockIdx.x;                // 0..2047
    const int jt = 63 - (wg >> 5);            // long q-tiles dispatched first
    const int bh = (wg & 7) * 4 + ((wg >> 3) & 3);   // bh pinned to one XCD
    const int q0 = jt * 32;
    const int nkt = (jt >> 1) + 1;
    const int lo = (wv * nkt) >> 2;           // this wave's key-tile range
    const int hi = ((wv + 1) * nkt) >> 2;
    const int b = bh >> 4, h = bh & 15;

    const unsigned short* Qh = Q + (size_t)bh * 2048 * 64;
    const char* Kg = (const char*)(K + (size_t)bh * 2048 * 64);
    const char* Vg = (const char*)(Vt + (size_t)bh * 64 * 2048);
    char* Kb = ldsKV[wv];
    char* Vb = ldsKV[wv] + 8192;
    char* Pb = ldsP[wv];

    bf16x8 qa[2][2];
#pragma unroll
    for (int mf = 0; mf < 2; mf++)
#pragma unroll
        for (int ks = 0; ks < 2; ks++)
            qa[mf][ks] = *(const bf16x8*)(Qh + (size_t)(q0 + mf * 16 + l15) * 64 +
                                          ks * 32 + lg * 8);

    auto stage = [&](int k0) {
        const char* kg = Kg + (size_t)k0 * 128;          // K rows contiguous
        const char* vg = Vg + (size_t)k0 * 2;            // V^T row stride 4096B
#pragma unroll
        for (int ii = 0; ii < 8; ii++) {
            gl_lds16(kg + (ii * 8 + lrow) * 128 + swz, Kb + ii * 1024);
            gl_lds16(vg + (size_t)(ii * 8 + lrow) * 4096 + swz, Vb + ii * 1024);
        }
    };

    f32x4 oacc[2][4] = {};
    float mi[2] = {-1e30f, -1e30f}, li[2] = {0.f, 0.f};

    if (lo < hi) {
        stage(lo * 64);
        for (int kt = lo; kt < hi; kt++) {
            const int k0 = kt * 64;
            SWAIT_VM0();                       // staged K/V tile landed
            bf16x8 kb[2][4], vb[2][4];
#pragma unroll
            for (int ks = 0; ks < 2; ks++)
#pragma unroll
                for (int nf = 0; nf < 4; nf++) {
                    int row = nf * 16 + l15;
                    kb[ks][nf] = *(const bf16x8*)(
                        Kb + row * 128 + ((ks * 64 + lg * 16) ^ ((row & 7) << 4)));
                }
#pragma unroll
            for (int ks = 0; ks < 2; ks++)
#pragma unroll
                for (int df = 0; df < 4; df++) {
                    int row = df * 16 + l15;
                    vb[ks][df] = *(const bf16x8*)(
                        Vb + row * 128 + ((ks * 64 + lg * 16) ^ ((row & 7) << 4)));
                }
            // S^T = K Q^T : out col(l15)=q-row, out row(lg*4+j)=key
            f32x4 s[2][4] = {};
#pragma unroll
            for (int ks = 0; ks < 2; ks++)
#pragma unroll
                for (int mf = 0; mf < 2; mf++)
#pragma unroll
                    for (int nf = 0; nf < 4; nf++)
                        s[mf][nf] = MFMA16(kb[ks][nf], qa[mf][ks], s[mf][nf]);
            SWAIT_LGKM0();                     // K/V frags drained to regs
            if (kt + 1 < hi) stage(k0 + 64);   // prefetch next tile (DMA)
            const bool maskt = (kt == nkt - 1);
            // ---- online softmax (log2 domain; Q pre-scaled by QSC) ----
#pragma unroll
            for (int mf = 0; mf < 2; mf++) {
                if (maskt) {
                    int qrow = q0 + mf * 16 + l15;
#pragma unroll
                    for (int nf = 0; nf < 4; nf++)
#pragma unroll
                        for (int j = 0; j < 4; j++)
                            if (k0 + nf * 16 + lg * 4 + j > qrow)
                                s[mf][nf][j] = -1e30f;
                }
                f32x4 t01 = fmax4(s[mf][0], s[mf][1]);
                f32x4 t23 = fmax4(s[mf][2], s[mf][3]);
                f32x4 tm = fmax4(t01, t23);
                float rmax = fmaxf(fmaxf(tm[0], tm[1]), fmaxf(tm[2], tm[3]));
                rmax = fmaxf(rmax, __shfl_xor(rmax, 16));
                rmax = fmaxf(rmax, __shfl_xor(rmax, 32));
                const float mnew = fmaxf(mi[mf], rmax);
                const float alpha = exp2f(mi[mf] - mnew);
                mi[mf] = mnew;
                float rsum = 0.f;
#pragma unroll
                for (int nf = 0; nf < 4; nf++)
#pragma unroll
                    for (int j = 0; j < 4; j++) {
                        float p = exp2f(s[mf][nf][j] - mnew);
                        s[mf][nf][j] = p;
                        rsum += p;
                    }
                rsum += __shfl_xor(rsum, 16);
                rsum += __shfl_xor(rsum, 32);
                li[mf] = li[mf] * alpha + rsum;
#pragma unroll
                for (int j = 0; j < 4; j++) {
                    float aj = __shfl(alpha, lg * 4 + j);
#pragma unroll
                    for (int df = 0; df < 4; df++) oacc[mf][df][j] *= aj;
                }
            }
            // ---- O += P @ V, double-pumped through 2KB P half-buffer ----
#pragma unroll
            for (int ksh = 0; ksh < 2; ksh++) {
#pragma unroll
                for (int mf = 0; mf < 2; mf++) {
                    int row = mf * 16 + l15;
#pragma unroll
                    for (int nf2 = 0; nf2 < 2; nf2++) {
                        bf16x4 pk;
#pragma unroll
                        for (int j = 0; j < 4; j++)
                            pk[j] = (__bf16)s[mf][ksh * 2 + nf2][j];
                        *(bf16x4*)(Pb + row * 64 +
                                   ((nf2 * 32 + lg * 8) ^ ((row & 3) << 4))) = pk;
                    }
                }
                bf16x8 pa[2];
#pragma unroll
                for (int mf = 0; mf < 2; mf++) {
                    int row = mf * 16 + l15;
                    pa[mf] = *(const bf16x8*)(
                        Pb + row * 64 + ((lg * 16) ^ ((row & 3) << 4)));
                }
#pragma unroll
                for (int mf = 0; mf < 2; mf++)
#pragma unroll
                    for (int df = 0; df < 4; df++)
                        oacc[mf][df] = MFMA16(pa[mf], vb[ksh][df], oacc[mf][df]);
            }
        }
    }

    // ---- publish partials (own KV slice is dead now) ----
    float* part = (float*)ldsKV[wv];          // [32 rows][68 floats] padded
#pragma unroll
    for (int mf = 0; mf < 2; mf++)
#pragma unroll
        for (int df = 0; df < 4; df++)
#pragma unroll
            for (int j = 0; j < 4; j++)
                part[(mf * 16 + lg * 4 + j) * 68 + df * 16 + l15] =
                    oacc[mf][df][j];
    if (lg == 0) {
#pragma unroll
        for (int mf = 0; mf < 2; mf++) {
            ml[wv][mf * 16 + l15][0] = mi[mf];
            ml[wv][mf * 16 + l15][1] = li[mf];
        }
    }
    __syncthreads();
    // ---- merge: wave wv handles rows [wv*8, wv*8+8), lane = column d ----
#pragma unroll
    for (int rr = 0; rr < 8; rr++) {
        const int row = wv * 8 + rr;
        float m01 = fmaxf(ml[0][row][0], ml[1][row][0]);
        float m23 = fmaxf(ml[2][row][0], ml[3][row][0]);
        float m = fmaxf(m01, m23);
        float ssum = 0.f, ov = 0.f;
#pragma unroll
        for (int v = 0; v < 4; v++) {
            float sv = exp2f(ml[v][row][0] - m);
            ssum += ml[v][row][1] * sv;
            ov += ((const float*)ldsKV[v])[row * 68 + lane] * sv;
        }
        O[((size_t)(b * 2048 + q0 + row)) * 1024 + h * 64 + lane] =
            f2bf(ov / ssum);
    }
}

// ---------------------------------------------------------------------------
extern "C" void kernel_launch(void* const* d_in, const int* in_sizes, int n_in,
                              void* d_out, int out_size, void* d_ws, size_t ws_size,
                              hipStream_t stream) {
    const float* x     = (const float*)d_in[0];
    const float* w_qkv = (const float*)d_in[1];
    const float* w_out = (const float*)d_in[2];
    float* out = (float*)d_out;
    char* ws = (char*)d_ws;
    const size_t MB = 1024 * 1024;

    unsigned short* xb    = (unsigned short*)(ws);             //  8 MB [4096][1024]
    unsigned short* wqkvt = (unsigned short*)(ws + 8 * MB);    //  6 MB [3072][1024]
    unsigned short* woutt = (unsigned short*)(ws + 14 * MB);   //  2 MB [1024][1024]
    unsigned short* qh    = (unsigned short*)(ws + 16 * MB);   //  8 MB [B,H,T,Dh]
    unsigned short* kh    = (unsigned short*)(ws + 24 * MB);   //  8 MB [B,H,T,Dh]
    unsigned short* vt    = (unsigned short*)(ws + 32 * MB);   //  8 MB [B,H,Dh,T]
    unsigned short* ao    = (unsigned short*)(ws + 40 * MB);   //  8 MB [4096][1024]
    float2* cst = (float2*)(ws + 48 * MB);                     // 512 KB

    cast_f32_bf16<<<4096, 256, 0, stream>>>(x, xb, (4096 * 1024) / 4);
    transpose_cast<<<dim3(96, 32), 256, 0, stream>>>(w_qkv, wqkvt, 1024, 3072);
    transpose_cast<<<dim3(32, 32), 256, 0, stream>>>(w_out, woutt, 1024, 1024);
    rope_tables<<<256, 256, 0, stream>>>(cst);

    gemm_bt<0><<<dim3(32, 24), 256, 0, stream>>>(xb, wqkvt, qh, kh, vt, nullptr,
                                                 cst, 4096, 3072, 1024);
    attn_fwd<<<2048, 256, 0, stream>>>(qh, kh, vt, ao);
    gemm_bt<1><<<dim3(32, 8), 256, 0, stream>>>(ao, woutt, nullptr, nullptr,
                                                nullptr, out, nullptr,
                                                4096, 1024, 1024);
}